// Round 5
// baseline (140.836 us; speedup 1.0000x reference)
//
#include <hip/hip_runtime.h>
#include <hip/hip_bf16.h>
#include <math.h>

// Problem constants (reference: N=16384, D=128, T=0.07)
#define NROWS 16384
#define DDIM  128
constexpr float TEMP = 0.07f;
// Pre-scale trick: x *= sqrt(log2(e)/T) so MFMA emits acc = S*<xi,xj> and
// row_lse = ln(sum exp2(acc)) exactly (max term 2^20.6, no overflow).

typedef __attribute__((ext_vector_type(8))) short bf16x8;
typedef __attribute__((ext_vector_type(4))) float f32x4;

__device__ __forceinline__ unsigned short f2b(float f) {
  unsigned int u = __float_as_uint(f);
  u += 0x7fffu + ((u >> 16) & 1u);
  return (unsigned short)(u >> 16);
}

// async 16B global -> LDS (lds dest = wave-uniform base + lane*16)
__device__ __forceinline__ void gload_lds16(const unsigned short* g, unsigned short* l) {
  __builtin_amdgcn_global_load_lds(
      (const __attribute__((address_space(1))) unsigned int*)g,
      (__attribute__((address_space(3))) unsigned int*)l, 16, 0, 0);
}

// Convert + pre-scale; also zero rowsum/accum/cnt.
__global__ void convert_k(const float* __restrict__ x, unsigned short* __restrict__ xb,
                          float* __restrict__ rowsum, float* __restrict__ accum,
                          int* __restrict__ cnt) {
  const float R = 4.53981419f;  // sqrt(log2(e)/T)
  int i = (blockIdx.x * blockDim.x + threadIdx.x) * 4;
  float4 v = *(const float4*)(x + i);
  ushort4 o;
  o.x = f2b(v.x * R); o.y = f2b(v.y * R); o.z = f2b(v.z * R); o.w = f2b(v.w * R);
  *(ushort4*)(xb + i) = o;
  if (blockIdx.x < 16) {
    float4 z = {0.f, 0.f, 0.f, 0.f};
    *(float4*)(rowsum + blockIdx.x * 1024 + threadIdx.x * 4) = z;
  }
  if (blockIdx.x == 16 && threadIdx.x == 0) { *accum = 0.f; *cnt = 0; }
}

// Triangular Gram: block (I,d) -> J=(I+d)%128 computes the 128x128 tile
// (rows I-block, cols J-block) ONCE. Row-sums of exp2 go to rowsum[rows];
// by symmetry its COL-sums are row-sums of the mirror tile -> rowsum[cols],
// except d==0 (diagonal, self-complete) and d==64 (pair computed from both
// sides, rows-only each). Covers every (i,j) exactly once; 8320 tiles vs
// 16384 full = 50.8% of the MFMA/exp2 work.
// LDS J-panel layout: 16B chunk (col,kc), kc=k/8 in [0,16): physical chunk
// p = col*16 + (kc ^ (col&15)) -> staging is fully coalesced per call AND
// consumer ds_read_b128 is 2-way-bank-aliased only (free, m136).
__global__ __launch_bounds__(256, 4)
void gram_tri_k(const unsigned short* __restrict__ xb, float* __restrict__ rowsum) {
  __shared__ unsigned short lB[128 * DDIM];   // 32 KB J-panel
  const int tid = threadIdx.x;
  const int wave = tid >> 6, lane = tid & 63;
  const int l15 = lane & 15, q = lane >> 4;
  const int I = blockIdx.x & 127;
  const int d = blockIdx.x >> 7;              // 0..64
  const int J = (I + d) & 127;
  const bool addCols = (d != 0) && (d != 64);
  const int rI = I * 128, rJ = J * 128;
  const int h = wave >> 1, chalf = wave & 1;  // row-half / col-half of this wave

  // stage J-panel -> LDS: 8 async rounds; round rr, this wave+lane stages
  // physical chunk rr*256 + wave*64 + lane -> col = rr*16 + wave*4 + q,
  // kcLog = l15 ^ (wave*4+q). Per call: 4 full 256B rows, permuted in-row.
  {
    const unsigned short* gJ = xb + (size_t)rJ * DDIM;
    const int colB = wave * 4 + q;
    const int kcLog = l15 ^ colB;
#pragma unroll
    for (int rr = 0; rr < 8; ++rr)
      gload_lds16(gJ + (rr * 16 + colB) * DDIM + kcLog * 8,
                  &lB[(rr * 256 + wave * 64) * 8]);
  }

  // A frags from global (L2-resident), overlapping the staging.
  // 16x16x32 A layout: m = l15, k = q*8 + j -> 16B contiguous per lane.
  bf16x8 af[4][4];
  const unsigned short* gA = xb + (size_t)(rI + h * 64 + l15) * DDIM + q * 8;
#pragma unroll
  for (int rt = 0; rt < 4; ++rt)
#pragma unroll
    for (int kt = 0; kt < 4; ++kt)
      af[rt][kt] = *(const bf16x8*)(gA + rt * 16 * DDIM + kt * 32);

  float rs[4][4], cs[4];
#pragma unroll
  for (int rt = 0; rt < 4; ++rt)
#pragma unroll
    for (int r = 0; r < 4; ++r) rs[rt][r] = 0.f;

  __syncthreads();   // drains vmcnt -> panel ready (A frags waited by compiler)

#pragma unroll
  for (int ct = 0; ct < 4; ++ct) {
    const int colb = chalf * 64 + ct * 16 + l15;
    bf16x8 bf[4];
#pragma unroll
    for (int kt = 0; kt < 4; ++kt)
      bf[kt] = *(const bf16x8*)&lB[colb * DDIM + (((kt * 4 + q) ^ l15) << 3)];
    float csl = 0.f;
#pragma unroll
    for (int rt = 0; rt < 4; ++rt) {
      f32x4 a = {0.f, 0.f, 0.f, 0.f};
#pragma unroll
      for (int kt = 0; kt < 4; ++kt)
        a = __builtin_amdgcn_mfma_f32_16x16x32_bf16(af[rt][kt], bf[kt], a, 0, 0, 0);
      // C/D layout: col = l15, row = q*4 + r
#pragma unroll
      for (int r = 0; r < 4; ++r) {
        float e = __builtin_amdgcn_exp2f(a[r]);
        rs[rt][r] += e;
        csl += e;
      }
    }
    cs[ct] = csl;
  }

  // row-sums: reduce over the 16 cols (l15) sharing each row
#pragma unroll
  for (int m = 1; m <= 8; m <<= 1)
#pragma unroll
    for (int rt = 0; rt < 4; ++rt)
#pragma unroll
      for (int r = 0; r < 4; ++r)
        rs[rt][r] += __shfl_xor(rs[rt][r], m, 64);
  if (l15 == 0) {
#pragma unroll
    for (int rt = 0; rt < 4; ++rt)
#pragma unroll
      for (int r = 0; r < 4; ++r)
        atomicAdd(&rowsum[rI + h * 64 + rt * 16 + q * 4 + r], rs[rt][r]);
  }

  // col-sums (mirror rows): reduce over the 4 row-groups (q)
  if (addCols) {
#pragma unroll
    for (int m = 16; m <= 32; m <<= 1)
#pragma unroll
      for (int ct = 0; ct < 4; ++ct)
        cs[ct] += __shfl_xor(cs[ct], m, 64);
    if (q == 0) {
#pragma unroll
      for (int ct = 0; ct < 4; ++ct)
        atomicAdd(&rowsum[rJ + chalf * 64 + ct * 16 + l15], cs[ct]);
    }
  }
}

// 64 blocks reduce ln(rowsum); last block writes the scalar.
// loss = mean_i ln(rowsum_i)  (the 1/T shift cancelled into the pre-scale).
__global__ void finalize_k(const float* __restrict__ rowsum, float* __restrict__ accum,
                           int* __restrict__ cnt, float* __restrict__ out) {
  __shared__ float red[4];
  const int tid = threadIdx.x;
  float s = __logf(rowsum[blockIdx.x * 256 + tid]);
#pragma unroll
  for (int m = 1; m < 64; m <<= 1) s += __shfl_xor(s, m, 64);
  if ((tid & 63) == 0) red[tid >> 6] = s;
  __syncthreads();
  if (tid == 0) {
    atomicAdd(accum, red[0] + red[1] + red[2] + red[3]);
    __threadfence();
    int prev = atomicAdd(cnt, 1);
    if (prev == (int)gridDim.x - 1) {
      __threadfence();
      float a = __hip_atomic_load(accum, __ATOMIC_RELAXED, __HIP_MEMORY_SCOPE_AGENT);
      out[0] = a / (float)NROWS;
    }
  }
}

extern "C" void kernel_launch(void* const* d_in, const int* in_sizes, int n_in,
                              void* d_out, int out_size, void* d_ws, size_t ws_size,
                              hipStream_t stream) {
  const float* x = (const float*)d_in[0];
  float* out = (float*)d_out;
  unsigned short* xb = (unsigned short*)d_ws;                       // 4 MB
  float* rowsum = (float*)((char*)d_ws + (size_t)NROWS * DDIM * 2); // 64 KB
  float* accum = rowsum + NROWS;
  int* cnt = (int*)(accum + 1);

  convert_k<<<NROWS * DDIM / (256 * 4), 256, 0, stream>>>(x, xb, rowsum, accum, cnt);
  gram_tri_k<<<128 * 65, 256, 0, stream>>>(xb, rowsum);
  finalize_k<<<NROWS / 256, 256, 0, stream>>>(rowsum, accum, cnt, out);
}

// Round 7
// 126.425 us; speedup vs baseline: 1.1140x; 1.1140x over previous
//
#include <hip/hip_runtime.h>
#include <hip/hip_bf16.h>
#include <math.h>

// Problem constants (reference: N=16384, D=128, T=0.07)
#define NROWS 16384
#define DDIM  128
constexpr float TEMP = 0.07f;
// Pre-scale trick: x *= sqrt(log2(e)/T) so MFMA emits acc = S*<xi,xj> and
// row_lse = ln(sum exp2(acc)) exactly (max term 2^20.6, no overflow).

typedef __attribute__((ext_vector_type(8))) short bf16x8;
typedef __attribute__((ext_vector_type(4))) float f32x4;

__device__ __forceinline__ unsigned short f2b(float f) {
  unsigned int u = __float_as_uint(f);
  u += 0x7fffu + ((u >> 16) & 1u);
  return (unsigned short)(u >> 16);
}

// async 16B global -> LDS (lds dest = wave-uniform base + lane*16)
__device__ __forceinline__ void gload_lds16(const unsigned short* g, unsigned short* l) {
  __builtin_amdgcn_global_load_lds(
      (const __attribute__((address_space(1))) unsigned int*)g,
      (__attribute__((address_space(3))) unsigned int*)l, 16, 0, 0);
}

// Convert + pre-scale; zero accum/cnt.
__global__ void convert_k(const float* __restrict__ x, unsigned short* __restrict__ xb,
                          float* __restrict__ accum, int* __restrict__ cnt) {
  const float R = 4.53981419f;  // sqrt(log2(e)/T)
  int i = (blockIdx.x * blockDim.x + threadIdx.x) * 4;
  float4 v = *(const float4*)(x + i);
  ushort4 o;
  o.x = f2b(v.x * R); o.y = f2b(v.y * R); o.z = f2b(v.z * R); o.w = f2b(v.w * R);
  *(ushort4*)(xb + i) = o;
  if (blockIdx.x == 0 && threadIdx.x == 0) { *accum = 0.f; *cnt = 0; }
}

// Triangular Gram, multi-tile blocks, ZERO contended atomics.
// Block (I,s): A = I-panel (128 rows) register-resident; loops d-tiles
// s==0: d=0..8, else d=8s+1..8s+8 (union d=0..64 exactly once per I).
// Tile (I,d), J=(I+d)%128: computed once; exp2 row-sums accumulate in regs
// across tiles. ROW STORE (R6 bugfix): waves (h,chalf=0) and (h,chalf=1)
// each hold a 64-col half of the same rows -> combine through csbuf at the
// END, then ONE plain store per row by the chalf=0 wave (unique writer).
// Col-sums (mirror rows, d not in {0,64}): LDS-combined across waves ->
// 128 plain stores to colpart[d-1] (unique writer per (d,j)).
// J-panels double-buffered via async global_load_lds; XOR-swizzled layout:
// 16B chunk (col,kc): physical chunk p = col*16 + (kc ^ (col&15)) ->
// coalesced staging AND <=2-way bank alias on consumer ds_read_b128 (free).
// 512 threads = 8 waves; wave w: rows h*32 (h=w>>1, rt<2), cols chalf*64
// (chalf=w&1, ct<4). Dynamic LDS 2*32KB panels + 2KB csbuf = 67584 B.
__global__ __launch_bounds__(512, 4)
void gram_tri_k(const unsigned short* __restrict__ xb, float* __restrict__ rowpart,
                float* __restrict__ colpart) {
  extern __shared__ unsigned short smem[];
  unsigned short* b0 = smem;
  unsigned short* b1 = smem + 16384;
  float* csbuf = (float*)(smem + 32768);   // 512 floats

  const int tid = threadIdx.x;
  const int w = tid >> 6, lane = tid & 63;
  const int l15 = lane & 15, q = lane >> 4;
  const int I = (int)(blockIdx.x >> 3), s = (int)(blockIdx.x & 7);
  const int rI = I * 128;
  const int h = w >> 1, chalf = w & 1;
  const int dstart = (s == 0) ? 0 : 8 * s + 1;
  const int ntiles = (s == 0) ? 9 : 8;

  // A frags (fixed all tiles): rows rI + h*32 + rt*16 + l15, k = kt*32 + q*8
  bf16x8 af[2][4];
  const unsigned short* gA = xb + (size_t)(rI + h * 32 + l15) * DDIM + q * 8;
#pragma unroll
  for (int rt = 0; rt < 2; ++rt)
#pragma unroll
    for (int kt = 0; kt < 4; ++kt)
      af[rt][kt] = *(const bf16x8*)(gA + rt * 16 * DDIM + kt * 32);

  // stage tile 0 panel into b0: 4 rounds/wave; round rr stages physical
  // chunk (w*4+rr)*64+lane -> col = w*16+rr*4+q, kcLog = l15^(rr*4+q)
  {
    const unsigned short* gJ = xb + (size_t)(((I + dstart) & 127) * 128) * DDIM;
#pragma unroll
    for (int rr = 0; rr < 4; ++rr)
      gload_lds16(gJ + (w * 16 + rr * 4 + q) * DDIM + (l15 ^ (rr * 4 + q)) * 8,
                  b0 + (w * 4 + rr) * 512);
  }

  float rs[2][4];
#pragma unroll
  for (int rt = 0; rt < 2; ++rt)
#pragma unroll
    for (int r = 0; r < 4; ++r) rs[rt][r] = 0.f;

  for (int ti = 0; ti < ntiles; ++ti) {
    const int d = dstart + ti;
    const int rJ = ((I + d) & 127) * 128;
    __syncthreads();   // panel[ti&1] ready (vmcnt drained); csbuf(ti-1) consumed
    if (ti + 1 < ntiles) {
      const unsigned short* gJ = xb + (size_t)(((I + d + 1) & 127) * 128) * DDIM;
      unsigned short* bn = ((ti + 1) & 1) ? b1 : b0;
#pragma unroll
      for (int rr = 0; rr < 4; ++rr)
        gload_lds16(gJ + (w * 16 + rr * 4 + q) * DDIM + (l15 ^ (rr * 4 + q)) * 8,
                    bn + (w * 4 + rr) * 512);
    }
    const unsigned short* L = (ti & 1) ? b1 : b0;

    float cstile[4];
#pragma unroll
    for (int ct = 0; ct < 4; ++ct) {
      const int colb = chalf * 64 + ct * 16 + l15;
      bf16x8 bfr[4];
#pragma unroll
      for (int kt = 0; kt < 4; ++kt)
        bfr[kt] = *(const bf16x8*)&L[colb * DDIM + (((kt * 4 + q) ^ l15) << 3)];
      float csl = 0.f;
#pragma unroll
      for (int rt = 0; rt < 2; ++rt) {
        f32x4 a = {0.f, 0.f, 0.f, 0.f};
#pragma unroll
        for (int kt = 0; kt < 4; ++kt)
          a = __builtin_amdgcn_mfma_f32_16x16x32_bf16(af[rt][kt], bfr[kt], a, 0, 0, 0);
        // C/D layout: col = l15, row = q*4 + r
#pragma unroll
        for (int r = 0; r < 4; ++r) {
          float e = __builtin_amdgcn_exp2f(a[r]);
          rs[rt][r] += e;
          csl += e;
        }
      }
      cstile[ct] = csl;
    }

    // col partial: reduce over q (wave's 32 rows), stash per-h into csbuf
#pragma unroll
    for (int m = 16; m <= 32; m <<= 1)
#pragma unroll
      for (int ct = 0; ct < 4; ++ct)
        cstile[ct] += __shfl_xor(cstile[ct], m, 64);
    if (q == 0) {
#pragma unroll
      for (int ct = 0; ct < 4; ++ct)
        csbuf[h * 128 + chalf * 64 + ct * 16 + l15] = cstile[ct];
    }
    __syncthreads();   // csbuf ready
    if (d != 0 && d != 64 && tid < 128)
      colpart[(size_t)(d - 1) * NROWS + rJ + tid] =
          csbuf[tid] + csbuf[128 + tid] + csbuf[256 + tid] + csbuf[384 + tid];
  }

  // rows: reduce over the 16 cols (l15) within each wave's 64-col half...
#pragma unroll
  for (int m = 1; m <= 8; m <<= 1)
#pragma unroll
    for (int rt = 0; rt < 2; ++rt)
#pragma unroll
      for (int r = 0; r < 4; ++r)
        rs[rt][r] += __shfl_xor(rs[rt][r], m, 64);
  // ...then combine the two col-halves (chalf 0/1) through csbuf: chalf=1
  // stashes, chalf=0 adds and is the UNIQUE writer of rowpart slice s.
  __syncthreads();   // last tile's colpart store finished reading csbuf
  if (chalf == 1 && l15 == 0) {
#pragma unroll
    for (int rt = 0; rt < 2; ++rt)
#pragma unroll
      for (int r = 0; r < 4; ++r)
        csbuf[h * 32 + rt * 16 + q * 4 + r] = rs[rt][r];
  }
  __syncthreads();
  if (chalf == 0 && l15 == 0) {
#pragma unroll
    for (int rt = 0; rt < 2; ++rt)
#pragma unroll
      for (int r = 0; r < 4; ++r) {
        const int ro = h * 32 + rt * 16 + q * 4 + r;
        rowpart[(size_t)s * NROWS + rI + ro] = rs[rt][r] + csbuf[ro];
      }
  }
}

// 64 blocks x 256 threads: row i sums 8 rowpart + 63 colpart slices
// (coalesced), logs, block-reduces; last block writes mean.
__global__ void finalize_k(const float* __restrict__ rowpart, const float* __restrict__ colpart,
                           float* __restrict__ accum, int* __restrict__ cnt,
                           float* __restrict__ out) {
  __shared__ float red[4];
  const int tid = threadIdx.x;
  const int i = blockIdx.x * 256 + tid;
  float v = 0.f;
#pragma unroll
  for (int s2 = 0; s2 < 8; ++s2) v += rowpart[(size_t)s2 * NROWS + i];
#pragma unroll
  for (int d = 1; d < 64; ++d) v += colpart[(size_t)(d - 1) * NROWS + i];
  float s = __logf(v);
#pragma unroll
  for (int m = 1; m < 64; m <<= 1) s += __shfl_xor(s, m, 64);
  if ((tid & 63) == 0) red[tid >> 6] = s;
  __syncthreads();
  if (tid == 0) {
    atomicAdd(accum, red[0] + red[1] + red[2] + red[3]);
    __threadfence();
    int prev = atomicAdd(cnt, 1);
    if (prev == (int)gridDim.x - 1) {
      __threadfence();
      float a = __hip_atomic_load(accum, __ATOMIC_RELAXED, __HIP_MEMORY_SCOPE_AGENT);
      out[0] = a / (float)NROWS;
    }
  }
}

extern "C" void kernel_launch(void* const* d_in, const int* in_sizes, int n_in,
                              void* d_out, int out_size, void* d_ws, size_t ws_size,
                              hipStream_t stream) {
  const float* x = (const float*)d_in[0];
  float* out = (float*)d_out;
  // ws layout: xb 4 MB | rowpart 8x64KB | colpart 63x64KB | accum,cnt
  unsigned short* xb = (unsigned short*)d_ws;
  float* rowpart = (float*)((char*)d_ws + (size_t)NROWS * DDIM * 2);
  float* colpart = rowpart + (size_t)8 * NROWS;
  float* accum = colpart + (size_t)63 * NROWS;
  int* cnt = (int*)(accum + 1);

  (void)hipFuncSetAttribute((const void*)gram_tri_k,
                            hipFuncAttributeMaxDynamicSharedMemorySize, 67584);

  convert_k<<<NROWS * DDIM / (256 * 4), 256, 0, stream>>>(x, xb, accum, cnt);
  gram_tri_k<<<128 * 8, 512, 67584, stream>>>(xb, rowpart, colpart);
  finalize_k<<<NROWS / 256, 256, 0, stream>>>(rowpart, colpart, accum, cnt, out);
}